// Round 9
// baseline (107.901 us; speedup 1.0000x reference)
//
#include <hip/hip_runtime.h>

// i1e(x) = exp(-x)*I1(x) for x in [0.1, 100] (inputs strictly positive).
//
// z <= 8 : i1e = z * Q(z^2) * exp2(-z*log2e - 1), Q = Taylor of I1(z)/(z/2), k<=8.
// z >  8 : i1e = P(1/z) * rsqrt(z), deg-4, 1/sqrt(2*pi) folded in.
// Comparison floor is bf16 quantum (~9.8e-4); threshold 4.375e-3 absolute.
//
// R9: input is EXACTLY 256 MiB = exactly L3 capacity; cyclic re-scan under
// random replacement self-thrashes to ~50% hits (R8 measured FETCH = half).
// Fix: static partition — first 208 MiB loaded PLAIN (stays L3-resident
// across graph replays; NT traffic never evicts it), last 48 MiB loaded NT
// (always HBM). Stores stay NT (R5: plain stores cost +13us).
// Ledger: both-NT=105, none=118, NT-stores-only=92, partitioned=THIS.

typedef float v4f __attribute__((ext_vector_type(4)));

__device__ __forceinline__ float i1e_one(float z) {
    // ---- small branch: z <= 8 (Taylor, deg-8 Horner in w = z^2) ----
    float w = z * z;
    float q = 1.0427930e-15f;
    q = __fmaf_rn(q, w, 3.0035206e-13f);
    q = __fmaf_rn(q, w, 6.7278617e-11f);
    q = __fmaf_rn(q, w, 1.1302806e-8f);
    q = __fmaf_rn(q, w, 1.3563368e-6f);
    q = __fmaf_rn(q, w, 1.0850694e-4f);
    q = __fmaf_rn(q, w, 5.2083335e-3f);
    q = __fmaf_rn(q, w, 0.125f);
    q = __fmaf_rn(q, w, 1.0f);
    // 0.5*exp(-z) = exp2(-z*log2(e) - 1); v_exp_f32 computes 2^x
    float e  = __builtin_amdgcn_exp2f(__fmaf_rn(z, -1.44269504f, -1.0f));
    float small = z * q * e;

    // ---- large branch: z > 8 (asymptotic deg-4, 1/sqrt(2pi) folded in) ----
    float r = __frsqrt_rn(z);        // v_rsq_f32
    float u = r * r;                 // ~1/z, no divide
    float p = -0.057527543f;
    p = __fmaf_rn(p, u, -0.040907327f);
    p = __fmaf_rn(p, u, -0.046750878f);
    p = __fmaf_rn(p, u, -0.14960336f);
    p = __fmaf_rn(p, u,  0.39894228f);
    float large = p * r;

    return (z <= 8.0f) ? small : large;
}

__device__ __forceinline__ v4f i1e_v4(v4f v) {
    v4f o;
    o.x = i1e_one(v.x);
    o.y = i1e_one(v.y);
    o.z = i1e_one(v.z);
    o.w = i1e_one(v.w);
    return o;
}

__global__ void __launch_bounds__(256, 8)
ive_kernel(const float* __restrict__ in, float* __restrict__ out,
           int n4, int n, int cut4) {
    int tid    = blockIdx.x * blockDim.x + threadIdx.x;
    int stride = gridDim.x * blockDim.x;

    const v4f* in4  = reinterpret_cast<const v4f*>(in);
    v4f*       out4 = reinterpret_cast<v4f*>(out);

    int i = tid;
    for (; i + 3 * stride < n4; i += 4 * stride) {
        int i1 = i + stride, i2 = i + 2 * stride, i3 = i + 3 * stride;
        v4f a, b, c, d;
        if (i3 < cut4) {                 // all in the L3-pinned region
            a = in4[i];
            b = in4[i1];
            c = in4[i2];
            d = in4[i3];
        } else if (i >= cut4) {          // all in the streaming tail
            a = __builtin_nontemporal_load(in4 + i);
            b = __builtin_nontemporal_load(in4 + i1);
            c = __builtin_nontemporal_load(in4 + i2);
            d = __builtin_nontemporal_load(in4 + i3);
        } else {                         // straddle (rare, wave-uniform cut)
            a = (i  < cut4) ? in4[i]  : __builtin_nontemporal_load(in4 + i);
            b = (i1 < cut4) ? in4[i1] : __builtin_nontemporal_load(in4 + i1);
            c = (i2 < cut4) ? in4[i2] : __builtin_nontemporal_load(in4 + i2);
            d = (i3 < cut4) ? in4[i3] : __builtin_nontemporal_load(in4 + i3);
        }
        __builtin_nontemporal_store(i1e_v4(a), out4 + i);
        __builtin_nontemporal_store(i1e_v4(b), out4 + i1);
        __builtin_nontemporal_store(i1e_v4(c), out4 + i2);
        __builtin_nontemporal_store(i1e_v4(d), out4 + i3);
    }
    // cleanup: remaining float4s
    for (; i < n4; i += stride) {
        v4f a = (i < cut4) ? in4[i] : __builtin_nontemporal_load(in4 + i);
        __builtin_nontemporal_store(i1e_v4(a), out4 + i);
    }
    // scalar tail (n not divisible by 4)
    for (int j = 4 * n4 + tid; j < n; j += stride) {
        out[j] = i1e_one(in[j]);
    }
}

extern "C" void kernel_launch(void* const* d_in, const int* in_sizes, int n_in,
                              void* d_out, int out_size, void* d_ws, size_t ws_size,
                              hipStream_t stream) {
    const float* z   = (const float*)d_in[0];
    float*       out = (float*)d_out;
    int n  = in_sizes[0];
    int n4 = n >> 2;

    int block = 256;
    int grid  = 2048;                 // 256 CU x 8 blocks/CU, exactly resident
    int need  = (n4 + 4 * block - 1) / (4 * block);
    if (grid > need) grid = need;
    if (grid < 1) grid = 1;

    // Cacheable prefix: 208 MiB of the input (L3 = 256 MiB, keep 48 MiB slack).
    long long cut_ll = 208LL * 1024 * 1024 / 16;   // in float4 units
    int cut4 = (cut_ll > n4) ? n4 : (int)cut_ll;

    ive_kernel<<<grid, block, 0, stream>>>(z, out, n4, n, cut4);
}

// Round 10
// 83.937 us; speedup vs baseline: 1.2855x; 1.2855x over previous
//
#include <hip/hip_runtime.h>

// i1e(x) = exp(-x)*I1(x) for x in [0.1, 100] (inputs strictly positive).
//
// z <= 8 : i1e = z * Q(z^2) * exp2(-z*log2e - 1), Q = Taylor of I1(z)/(z/2), k<=8.
// z >  8 : i1e = P(1/z) * rsqrt(z), deg-4, 1/sqrt(2*pi) folded in.
// Comparison floor is bf16 quantum (~9.8e-4); threshold 4.375e-3 absolute.
//
// R10: single variable vs R8 (92us champ): ADDRESS MAPPING. Block-contiguous
// segments (16 KiB contiguous per block-iteration, 2048 sequential DRAM
// streams) instead of grid-strided chunks (8192 interleaved streams 8 MiB
// apart). Loads PLAIN (L3 gives ~50% hits on the exactly-256MiB input across
// replays), stores NT (keeps write stream out of L3; R5 proved +13us else).
// Ledger: both-NT=105, none=118, NT-stores-only=92, partition=108(dead).

typedef float v4f __attribute__((ext_vector_type(4)));

__device__ __forceinline__ float i1e_one(float z) {
    // ---- small branch: z <= 8 (Taylor, deg-8 Horner in w = z^2) ----
    float w = z * z;
    float q = 1.0427930e-15f;
    q = __fmaf_rn(q, w, 3.0035206e-13f);
    q = __fmaf_rn(q, w, 6.7278617e-11f);
    q = __fmaf_rn(q, w, 1.1302806e-8f);
    q = __fmaf_rn(q, w, 1.3563368e-6f);
    q = __fmaf_rn(q, w, 1.0850694e-4f);
    q = __fmaf_rn(q, w, 5.2083335e-3f);
    q = __fmaf_rn(q, w, 0.125f);
    q = __fmaf_rn(q, w, 1.0f);
    // 0.5*exp(-z) = exp2(-z*log2(e) - 1); v_exp_f32 computes 2^x
    float e  = __builtin_amdgcn_exp2f(__fmaf_rn(z, -1.44269504f, -1.0f));
    float small = z * q * e;

    // ---- large branch: z > 8 (asymptotic deg-4, 1/sqrt(2pi) folded in) ----
    float r = __frsqrt_rn(z);        // v_rsq_f32
    float u = r * r;                 // ~1/z, no divide
    float p = -0.057527543f;
    p = __fmaf_rn(p, u, -0.040907327f);
    p = __fmaf_rn(p, u, -0.046750878f);
    p = __fmaf_rn(p, u, -0.14960336f);
    p = __fmaf_rn(p, u,  0.39894228f);
    float large = p * r;

    return (z <= 8.0f) ? small : large;
}

__device__ __forceinline__ v4f i1e_v4(v4f v) {
    v4f o;
    o.x = i1e_one(v.x);
    o.y = i1e_one(v.y);
    o.z = i1e_one(v.z);
    o.w = i1e_one(v.w);
    return o;
}

__global__ void __launch_bounds__(256, 8)
ive_kernel(const float* __restrict__ in, float* __restrict__ out,
           int n4, int n, int seg) {
    const int t = threadIdx.x;
    const v4f* in4  = reinterpret_cast<const v4f*>(in);
    v4f*       out4 = reinterpret_cast<v4f*>(out);

    int start = blockIdx.x * seg;
    int end   = start + seg;
    if (end > n4) end = n4;

    int i = start + t;
    // depth-4 within the block's contiguous segment: 4 consecutive 4-KiB
    // lines per iteration (16 KiB contiguous per block-step)
    for (; i + 768 < end; i += 1024) {
        v4f a = in4[i];
        v4f b = in4[i + 256];
        v4f c = in4[i + 512];
        v4f d = in4[i + 768];
        __builtin_nontemporal_store(i1e_v4(a), out4 + i);
        __builtin_nontemporal_store(i1e_v4(b), out4 + i + 256);
        __builtin_nontemporal_store(i1e_v4(c), out4 + i + 512);
        __builtin_nontemporal_store(i1e_v4(d), out4 + i + 768);
    }
    // segment remainder (one 4-KiB line at a time)
    for (; i < end; i += 256) {
        v4f a = in4[i];
        __builtin_nontemporal_store(i1e_v4(a), out4 + i);
    }
    // scalar tail (n not divisible by 4), handled by the last block
    if (blockIdx.x == gridDim.x - 1) {
        for (int j = 4 * n4 + t; j < n; j += 256) {
            out[j] = i1e_one(in[j]);
        }
    }
}

extern "C" void kernel_launch(void* const* d_in, const int* in_sizes, int n_in,
                              void* d_out, int out_size, void* d_ws, size_t ws_size,
                              hipStream_t stream) {
    const float* z   = (const float*)d_in[0];
    float*       out = (float*)d_out;
    int n  = in_sizes[0];
    int n4 = n >> 2;

    const int block = 256;
    const int grid  = 2048;           // 256 CU x 8 blocks/CU, exactly resident
    // per-block contiguous segment, rounded up to a 1024-float4 group
    int seg = (n4 + grid - 1) / grid;
    seg = (seg + 1023) & ~1023;       // multiple of 256 threads x 4 chunks
    if (seg < 1024) seg = 1024;

    ive_kernel<<<grid, block, 0, stream>>>(z, out, n4, n, seg);
}